// Round 12
// baseline (848.554 us; speedup 1.0000x reference)
//
#include <hip/hip_runtime.h>
#include <hip/hip_bf16.h>

// ---------------------------------------------------------------------------
// DenoiseGCN fused kernel for MI355X (gfx950) — round 12.
// R11 post-mortem: VALU 57 / MFMA 22 / LDS ~20 — no pipe saturated; residual
// cost = phase-start L2 latency (B-frags issued cold after each barrier) at
// reg-capped 4 waves/SIMD. Fix (T14-lite): prefetch each mm2's first 2 ks of
// weight fragments (16 VGPR) BEFORE the preceding epilogue/barrier — L2
// latency hides under epilogue VALU; W1's prefetch overlaps the x-staging
// phase; head2's overlaps head1's epilogue. Remainder ks-loop unroll 2 keeps
// regs in the same 65-128 bracket. Residual LDS reads hoisted ahead of the
// shfl/math chain in the epilogue.
// ---------------------------------------------------------------------------

typedef __attribute__((ext_vector_type(8))) short bf16x8;
typedef __attribute__((ext_vector_type(4))) float f32x4;

#define NV 1024

// ws layout: bf16 region then f32 region
#define OFF_W1T   0        // [256][256] bf16, [n][k], pre-scaled 1/3
#define OFF_W2T   65536
#define OFF_W3T   131072
#define OFF_HW1T  196608
#define OFF_HW2T  262144   // [16][256]
#define BF16_ELEMS 266240
#define CW_BYTE   532480               // f32 cw[4][256]: W0c0,W0c1,res0c0,res0c1
#define TV_BYTE   536576               // f32 tv[512][256]
#define PREP_TOTAL (BF16_ELEMS + 1024)

__device__ __forceinline__ short f2bf(float f){
  __hip_bfloat16 h = __float2bfloat16(f);
  return *reinterpret_cast<short*>(&h);
}
__device__ __forceinline__ float silu_f(float v){
  float e = __expf(-v);
  return v * __builtin_amdgcn_rcpf(1.f + e);
}
__device__ __forceinline__ f32x4 zero4(){ f32x4 z = {0.f,0.f,0.f,0.f}; return z; }
__device__ __forceinline__ unsigned int pack2_silu(float s0, float s1){
  return (unsigned int)(unsigned short)f2bf(silu_f(s0))
       | ((unsigned int)(unsigned short)f2bf(silu_f(s1)) << 16);
}

// ---------------------------------------------------------------------------
// prep: W1..W3 (x1/3), hW1 -> bf16 [n][k]; hW2 -> bf16 [16][256];
// cw f32 = coord rows of W0/res0.
// ---------------------------------------------------------------------------
__global__ void prep_kernel(const float* __restrict__ W0, const float* __restrict__ res0,
                            const float* __restrict__ W1, const float* __restrict__ W2,
                            const float* __restrict__ W3, const float* __restrict__ hW1,
                            const float* __restrict__ hW2, short* __restrict__ ws){
  int idx = blockIdx.x * 256 + threadIdx.x;
  if (idx >= PREP_TOTAL) return;
  if (idx < BF16_ELEMS){
    float v;
    if (idx < 262144){
      int seg = idx >> 16;
      int r2 = idx & 65535;
      int n = r2 >> 8, k = r2 & 255;
      const float* src = (seg == 0) ? W1 : (seg == 1) ? W2 : (seg == 2) ? W3 : hW1;
      v = src[k * 256 + n];
      if (seg < 3) v *= (1.f / 3.f);
    } else {
      int rem = idx - 262144;
      int n = rem >> 8, k = rem & 255;
      v = (n < 2) ? hW2[k * 2 + n] : 0.f;
    }
    ws[idx] = f2bf(v);
  } else {
    int i = idx - BF16_ELEMS;           // 0..1023
    int d = i >> 8, n = i & 255;
    float v = (d < 2) ? W0[d * 256 + n] : res0[(d - 2) * 256 + n];
    ((float*)((char*)ws + CW_BYTE))[i] = v;
  }
}

// ---------------------------------------------------------------------------
// temb+tv: tmb = silu(sinusoidal(t) @ time_W + time_b)  (128)
//          tv[n] = b0[n] + sum_k tmb[k] * (W0[k+2][n] + res0[k+2][n])  (f32)
// ---------------------------------------------------------------------------
__global__ void temb_kernel(const int* __restrict__ t, const float* __restrict__ tW,
                            const float* __restrict__ tb, const float* __restrict__ W0,
                            const float* __restrict__ res0, const float* __restrict__ b0,
                            float* __restrict__ tv){
  __shared__ float sc[128];
  __shared__ float tmb[128];
  int b = blockIdx.x, n = threadIdx.x;  // 256 threads
  float tvt = (float)t[b];
  if (n < 128){
    int j = n & 63;
    float fr = __expf(-9.210340371976184f * (float)j * (1.f / 63.f));
    float ang = tvt * fr;
    sc[n] = (n < 64) ? sinf(ang) : cosf(ang);
  }
  __syncthreads();
  if (n < 128){
    float acc = tb[n];
    #pragma unroll 8
    for (int k = 0; k < 128; ++k) acc += sc[k] * tW[k * 128 + n];
    tmb[n] = silu_f(acc);
  }
  __syncthreads();
  float acc2 = b0[n];
  #pragma unroll 4
  for (int k = 0; k < 128; ++k)
    acc2 += tmb[k] * (W0[(k + 2) * 256 + n] + res0[(k + 2) * 256 + n]);
  tv[b * 256 + n] = acc2;
}

// ---------------------------------------------------------------------------
// prefetch first 2 ks of a weight panel (4 frags = 16 VGPR)
// ---------------------------------------------------------------------------
__device__ __forceinline__ void pf2(const short* __restrict__ wb, bf16x8 pf[4]){
  pf[0] = *(const bf16x8*)(wb);            // tile0 ks0
  pf[1] = *(const bf16x8*)(wb + 256);      // tile1 ks0
  pf[2] = *(const bf16x8*)(wb + 32);       // tile0 ks1
  pf[3] = *(const bf16x8*)(wb + 256 + 32); // tile1 ks1
}

// ---------------------------------------------------------------------------
// mm2 with prefetched ks0-1 (interleaved cols): acc[mt][0] ~ col n0+2*m15,
// acc[mt][1] ~ next col. A: row = 16*mt + (l&15); C rows (l>>4)*4+j.
// Remainder ks=2..7 at unroll 2 (bounded weight hoisting).
// setprio(1) favors MFMA-issuing waves once waves drift (T5).
// ---------------------------------------------------------------------------
__device__ __forceinline__ void mm2_pf(const char* hbuf, const short* __restrict__ wb,
                                       const bf16x8 pf[4], int m15, int g,
                                       f32x4 acc[5][2]){
  __builtin_amdgcn_s_setprio(1);
  #pragma unroll
  for (int ks = 0; ks < 2; ++ks){
    const int kb = ks * 64 + g * 16;
    #pragma unroll
    for (int mt = 0; mt < 5; ++mt){
      const int row = mt * 16 + m15;
      bf16x8 a = *(const bf16x8*)(hbuf + row * 512 + (kb ^ ((row & 7) << 4)));
      acc[mt][0] = __builtin_amdgcn_mfma_f32_16x16x32_bf16(a, ks ? pf[2] : pf[0], acc[mt][0], 0, 0, 0);
      acc[mt][1] = __builtin_amdgcn_mfma_f32_16x16x32_bf16(a, ks ? pf[3] : pf[1], acc[mt][1], 0, 0, 0);
    }
  }
  #pragma unroll 2
  for (int ks = 2; ks < 8; ++ks){
    bf16x8 bf0 = *(const bf16x8*)(wb + ks * 32);
    bf16x8 bf1 = *(const bf16x8*)(wb + 256 + ks * 32);
    const int kb = ks * 64 + g * 16;
    #pragma unroll
    for (int mt = 0; mt < 5; ++mt){
      const int row = mt * 16 + m15;
      bf16x8 a = *(const bf16x8*)(hbuf + row * 512 + (kb ^ ((row & 7) << 4)));
      acc[mt][0] = __builtin_amdgcn_mfma_f32_16x16x32_bf16(a, bf0, acc[mt][0], 0, 0, 0);
      acc[mt][1] = __builtin_amdgcn_mfma_f32_16x16x32_bf16(a, bf1, acc[mt][1], 0, 0, 0);
    }
  }
  __builtin_amdgcn_s_setprio(0);
}

// ---------------------------------------------------------------------------
// Fused GCN. Grid (16, 512). 512 thr = 8 waves, wave w owns cols [32w,32w+32)
// (interleaved pairing). LDS: hA + hB 40KB each; cc (80 x f32x4) overlays hB
// during L0. Row r <-> vertex (v0+r-4) mod 1024. Flow:
// stage cc->hB | L0: cc->hA | L1: hA->hB | L2: hB->hA | L3: hA->hB |
// head1: hB->hA | head2: hA->out.  6 barriers. Weight pf issued one phase
// early (under the previous epilogue / staging) to hide L2 latency.
// ---------------------------------------------------------------------------
__global__ __launch_bounds__(512, 4)
void gcn_fused(const float* __restrict__ x, const short* __restrict__ ws,
               const float* __restrict__ tvp, const float* __restrict__ cwf,
               const float* __restrict__ b1p, const float* __restrict__ b2p,
               const float* __restrict__ b3p, const float* __restrict__ hb1p,
               const float* __restrict__ hb2p, float* __restrict__ out){
  extern __shared__ char lds[];
  char* const hA = lds;
  char* const hB = lds + 40960;
  const int tid = threadIdx.x;
  const int lane = tid & 63, wid = tid >> 6;
  const int m15 = lane & 15, g = lane >> 4;
  const int n0 = wid * 32;
  const int col0 = n0 + 2 * m15;
  const int cb2 = col0 * 2;             // byte col of this thread's col pair
  const int b = blockIdx.y, v0 = blockIdx.x * 64;

  const int wrow = (n0 + 2 * m15) * 256 + g * 8;
  const short* const wb1 = ws + OFF_W1T + wrow;
  const short* const wb2 = ws + OFF_W2T + wrow;
  const short* const wb3 = ws + OFF_W3T + wrow;
  const short* const wbh = ws + OFF_HW1T + wrow;

  bf16x8 pf[4];
  pf2(wb1, pf);                         // W1 prefetch overlaps staging + L0

  // ---- stage cc[r] = (cagg0, cagg1, c0, c1) f32 into hB[0:1280) ----
  if (tid < 80){
    const int r = tid;
    const float* xb = x + b * 2048;
    int vm = (v0 + r - 5) & (NV - 1);
    int vc = (v0 + r - 4) & (NV - 1);
    int vp = (v0 + r - 3) & (NV - 1);
    float c0m = xb[vm * 2], c1m = xb[vm * 2 + 1];
    float c0c = xb[vc * 2], c1c = xb[vc * 2 + 1];
    float c0p = xb[vp * 2], c1p = xb[vp * 2 + 1];
    f32x4 cc;
    cc[0] = (c0m + c0c + c0p) * (1.f / 3.f);
    cc[1] = (c1m + c1c + c1p) * (1.f / 3.f);
    cc[2] = c0c;
    cc[3] = c1c;
    *(f32x4*)(hB + r * 16) = cc;
  }
  __syncthreads();

  // ---- layer 0 (rank-5): h1 = silu(tv + cagg@W0c + c@res0c): cc -> hA ----
  {
    const float2 tv2 = *(const float2*)(tvp + b * 256 + col0);
    const float2 wA = *(const float2*)(cwf + col0);
    const float2 wB = *(const float2*)(cwf + 256 + col0);
    const float2 wC = *(const float2*)(cwf + 512 + col0);
    const float2 wD = *(const float2*)(cwf + 768 + col0);
    #pragma unroll
    for (int mt = 0; mt < 5; ++mt){
      const int row0 = mt * 16 + g * 4;
      #pragma unroll
      for (int j = 0; j < 4; ++j){
        const int row = row0 + j;
        const f32x4 cc = *(const f32x4*)(hB + row * 16);
        float s0 = tv2.x + cc[0] * wA.x + cc[1] * wB.x + cc[2] * wC.x + cc[3] * wD.x;
        float s1 = tv2.y + cc[0] * wA.y + cc[1] * wB.y + cc[2] * wC.y + cc[3] * wD.y;
        const int ad = row * 512 + (cb2 ^ ((row & 7) << 4));
        *(unsigned int*)(hA + ad) = pack2_silu(s0, s1);
      }
    }
  }
  __syncthreads();

  f32x4 acc[5][2];

  // ---- layers 1..3: h = silu(agg(h@W') + b + h); W' pre-scaled 1/3;
  //      agg via in-reg shfl; residual read from bin (read-only this phase);
  //      next layer's weight pf issued before the epilogue ----
  #pragma unroll
  for (int L = 0; L < 3; ++L){
    const char* bin  = (L & 1) ? hB : hA;
    char*       bout = (L & 1) ? hA : hB;
    const short* wbc = (L == 0) ? wb1 : (L == 1) ? wb2 : wb3;
    const float* bp = (L == 0 ? b1p : L == 1 ? b2p : b3p);
    const float2 bias = *(const float2*)(bp + col0);
    #pragma unroll
    for (int mt = 0; mt < 5; ++mt){ acc[mt][0] = zero4(); acc[mt][1] = zero4(); }
    mm2_pf(bin, wbc, pf, m15, g, acc);
    pf2((L == 0) ? wb2 : (L == 1) ? wb3 : wbh, pf);   // next phase's weights
    #pragma unroll
    for (int mt = 0; mt < 5; ++mt){
      const int row0 = mt * 16 + g * 4;
      // residual reads first (LDS latency overlaps shfl chain)
      unsigned int rr[4];
      #pragma unroll
      for (int j = 0; j < 4; ++j){
        const int row = row0 + j;
        rr[j] = *(const unsigned int*)(bin + row * 512 + (cb2 ^ ((row & 7) << 4)));
      }
      float pm0[2], pp3[2];
      #pragma unroll
      for (int nt = 0; nt < 2; ++nt){
        float upv = (g == 3) ? acc[mt > 0 ? mt - 1 : 0][nt][3] : acc[mt][nt][3];
        pm0[nt] = __shfl(upv, (lane + 48) & 63);
        float dnv = (g == 0) ? acc[mt < 4 ? mt + 1 : 4][nt][0] : acc[mt][nt][0];
        pp3[nt] = __shfl(dnv, (lane + 16) & 63);
      }
      #pragma unroll
      for (int j = 0; j < 4; ++j){
        const int row = row0 + j;
        const int ad = row * 512 + (cb2 ^ ((row & 7) << 4));
        union { unsigned int i; float f; } re, ro;
        re.i = rr[j] << 16;            // residual, even col
        ro.i = rr[j] & 0xffff0000u;    // residual, odd col
        float p0 = (j == 0) ? pm0[0] : acc[mt][0][j - 1];
        float n0v = (j == 3) ? pp3[0] : acc[mt][0][j + 1];
        float p1 = (j == 0) ? pm0[1] : acc[mt][1][j - 1];
        float n1v = (j == 3) ? pp3[1] : acc[mt][1][j + 1];
        float s0 = p0 + acc[mt][0][j] + n0v + bias.x + re.f;
        float s1 = p1 + acc[mt][1][j] + n1v + bias.y + ro.f;
        *(unsigned int*)(bout + ad) = pack2_silu(s0, s1);
      }
    }
    __syncthreads();
  }
  // h4 now in hB.

  // ---- head part 1: u = silu(h4 @ hW1 + hb1): hB -> hA ----
  {
    const float2 bias = *(const float2*)(hb1p + col0);
    #pragma unroll
    for (int mt = 0; mt < 5; ++mt){ acc[mt][0] = zero4(); acc[mt][1] = zero4(); }
    mm2_pf(hB, wbh, pf, m15, g, acc);
    // head2 weight prefetch (waves 0-4 use it after the barrier)
    bf16x8 h2a, h2b;
    {
      const short* wbo = ws + OFF_HW2T + m15 * 256 + g * 8;
      h2a = *(const bf16x8*)(wbo);
      h2b = *(const bf16x8*)(wbo + 32);
    }
    #pragma unroll
    for (int mt = 0; mt < 5; ++mt){
      const int row0 = mt * 16 + g * 4;
      #pragma unroll
      for (int j = 0; j < 4; ++j){
        const int row = row0 + j;
        const int ad = row * 512 + (cb2 ^ ((row & 7) << 4));
        *(unsigned int*)(hA + ad) =
            pack2_silu(acc[mt][0][j] + bias.x, acc[mt][1][j] + bias.y);
      }
    }
    __syncthreads();

    // ---- head part 2 (waves 0-4, one mt each): out = u @ hW2 + hb2 ----
    if (wid < 5){
      f32x4 a2 = zero4();
      const short* wbo = ws + OFF_HW2T + m15 * 256 + g * 8;
      const int row = wid * 16 + m15;
      const int rsw = row * 512;
      {
        bf16x8 a0 = *(const bf16x8*)(hA + rsw + ((g * 16) ^ ((row & 7) << 4)));
        a2 = __builtin_amdgcn_mfma_f32_16x16x32_bf16(a0, h2a, a2, 0, 0, 0);
        bf16x8 a1 = *(const bf16x8*)(hA + rsw + ((64 + g * 16) ^ ((row & 7) << 4)));
        a2 = __builtin_amdgcn_mfma_f32_16x16x32_bf16(a1, h2b, a2, 0, 0, 0);
      }
      #pragma unroll 2
      for (int ks = 2; ks < 8; ++ks){
        bf16x8 bfr = *(const bf16x8*)(wbo + ks * 32);
        const int kb = ks * 64 + g * 16;
        bf16x8 a = *(const bf16x8*)(hA + rsw + (kb ^ ((row & 7) << 4)));
        a2 = __builtin_amdgcn_mfma_f32_16x16x32_bf16(a, bfr, a2, 0, 0, 0);
      }
      if (m15 < 2){
        float bias = hb2p[m15];
        #pragma unroll
        for (int j = 0; j < 4; ++j){
          int orow = wid * 16 + g * 4 + j;
          if (orow >= 4 && orow < 68)
            out[b * 2048 + (v0 + orow - 4) * 2 + m15] = a2[j] + bias;
        }
      }
    }
  }
}

// ---------------------------------------------------------------------------
extern "C" void kernel_launch(void* const* d_in, const int* in_sizes, int n_in,
                              void* d_out, int out_size, void* d_ws, size_t ws_size,
                              hipStream_t stream){
  const float* x   = (const float*)d_in[0];
  const int*   t   = (const int*)  d_in[1];
  const float* tW  = (const float*)d_in[2];
  const float* tb  = (const float*)d_in[3];
  const float* W0  = (const float*)d_in[4];
  const float* b0  = (const float*)d_in[5];
  const float* W1  = (const float*)d_in[6];
  const float* b1  = (const float*)d_in[7];
  const float* W2  = (const float*)d_in[8];
  const float* b2  = (const float*)d_in[9];
  const float* W3  = (const float*)d_in[10];
  const float* b3  = (const float*)d_in[11];
  const float* res0= (const float*)d_in[12];
  const float* hW1 = (const float*)d_in[13];
  const float* hb1 = (const float*)d_in[14];
  const float* hW2 = (const float*)d_in[15];
  const float* hb2 = (const float*)d_in[16];
  short* ws  = (short*)d_ws;
  float* tvp = (float*)((char*)d_ws + TV_BYTE);
  float* cwf = (float*)((char*)d_ws + CW_BYTE);
  float* out = (float*)d_out;

  hipFuncSetAttribute((const void*)gcn_fused,
                      hipFuncAttributeMaxDynamicSharedMemorySize, 81920);

  prep_kernel<<<dim3((PREP_TOTAL + 255) / 256), dim3(256), 0, stream>>>(
      W0, res0, W1, W2, W3, hW1, hW2, ws);
  temb_kernel<<<dim3(512), dim3(256), 0, stream>>>(t, tW, tb, W0, res0, b0, tvp);
  gcn_fused<<<dim3(16, 512), dim3(512), 81920, stream>>>(
      x, ws, tvp, cwf, b1, b2, b3, hb1, hb2, out);
}

// Round 13
// 805.448 us; speedup vs baseline: 1.0535x; 1.0535x over previous
//
#include <hip/hip_runtime.h>
#include <hip/hip_bf16.h>

// ---------------------------------------------------------------------------
// DenoiseGCN fused kernel for MI355X (gfx950) — round 13.
// R12 post-mortem: pf[4] live ACROSS the epilogue peak -> spill (643MB).
// Fix: identical prefetch but issued AFTER the epilogue stores, right before
// __syncthreads — the barrier's vmcnt(0) drain completes the loads during
// the wave-skew wait; live range excludes the epilogue peak.
// sched_barrier(0) before each pf2 pins the loads below the epilogue
// (prevents the scheduler recreating R12's long range). Base = R11 (711us).
// ---------------------------------------------------------------------------

typedef __attribute__((ext_vector_type(8))) short bf16x8;
typedef __attribute__((ext_vector_type(4))) float f32x4;

#define NV 1024

// ws layout: bf16 region then f32 region
#define OFF_W1T   0        // [256][256] bf16, [n][k], pre-scaled 1/3
#define OFF_W2T   65536
#define OFF_W3T   131072
#define OFF_HW1T  196608
#define OFF_HW2T  262144   // [16][256]
#define BF16_ELEMS 266240
#define CW_BYTE   532480               // f32 cw[4][256]: W0c0,W0c1,res0c0,res0c1
#define TV_BYTE   536576               // f32 tv[512][256]
#define PREP_TOTAL (BF16_ELEMS + 1024)

__device__ __forceinline__ short f2bf(float f){
  __hip_bfloat16 h = __float2bfloat16(f);
  return *reinterpret_cast<short*>(&h);
}
__device__ __forceinline__ float silu_f(float v){
  float e = __expf(-v);
  return v * __builtin_amdgcn_rcpf(1.f + e);
}
__device__ __forceinline__ f32x4 zero4(){ f32x4 z = {0.f,0.f,0.f,0.f}; return z; }
__device__ __forceinline__ unsigned int pack2_silu(float s0, float s1){
  return (unsigned int)(unsigned short)f2bf(silu_f(s0))
       | ((unsigned int)(unsigned short)f2bf(silu_f(s1)) << 16);
}

// ---------------------------------------------------------------------------
// prep: W1..W3 (x1/3), hW1 -> bf16 [n][k]; hW2 -> bf16 [16][256];
// cw f32 = coord rows of W0/res0.
// ---------------------------------------------------------------------------
__global__ void prep_kernel(const float* __restrict__ W0, const float* __restrict__ res0,
                            const float* __restrict__ W1, const float* __restrict__ W2,
                            const float* __restrict__ W3, const float* __restrict__ hW1,
                            const float* __restrict__ hW2, short* __restrict__ ws){
  int idx = blockIdx.x * 256 + threadIdx.x;
  if (idx >= PREP_TOTAL) return;
  if (idx < BF16_ELEMS){
    float v;
    if (idx < 262144){
      int seg = idx >> 16;
      int r2 = idx & 65535;
      int n = r2 >> 8, k = r2 & 255;
      const float* src = (seg == 0) ? W1 : (seg == 1) ? W2 : (seg == 2) ? W3 : hW1;
      v = src[k * 256 + n];
      if (seg < 3) v *= (1.f / 3.f);
    } else {
      int rem = idx - 262144;
      int n = rem >> 8, k = rem & 255;
      v = (n < 2) ? hW2[k * 2 + n] : 0.f;
    }
    ws[idx] = f2bf(v);
  } else {
    int i = idx - BF16_ELEMS;           // 0..1023
    int d = i >> 8, n = i & 255;
    float v = (d < 2) ? W0[d * 256 + n] : res0[(d - 2) * 256 + n];
    ((float*)((char*)ws + CW_BYTE))[i] = v;
  }
}

// ---------------------------------------------------------------------------
// temb+tv: tmb = silu(sinusoidal(t) @ time_W + time_b)  (128)
//          tv[n] = b0[n] + sum_k tmb[k] * (W0[k+2][n] + res0[k+2][n])  (f32)
// ---------------------------------------------------------------------------
__global__ void temb_kernel(const int* __restrict__ t, const float* __restrict__ tW,
                            const float* __restrict__ tb, const float* __restrict__ W0,
                            const float* __restrict__ res0, const float* __restrict__ b0,
                            float* __restrict__ tv){
  __shared__ float sc[128];
  __shared__ float tmb[128];
  int b = blockIdx.x, n = threadIdx.x;  // 256 threads
  float tvt = (float)t[b];
  if (n < 128){
    int j = n & 63;
    float fr = __expf(-9.210340371976184f * (float)j * (1.f / 63.f));
    float ang = tvt * fr;
    sc[n] = (n < 64) ? sinf(ang) : cosf(ang);
  }
  __syncthreads();
  if (n < 128){
    float acc = tb[n];
    #pragma unroll 8
    for (int k = 0; k < 128; ++k) acc += sc[k] * tW[k * 128 + n];
    tmb[n] = silu_f(acc);
  }
  __syncthreads();
  float acc2 = b0[n];
  #pragma unroll 4
  for (int k = 0; k < 128; ++k)
    acc2 += tmb[k] * (W0[(k + 2) * 256 + n] + res0[(k + 2) * 256 + n]);
  tv[b * 256 + n] = acc2;
}

// ---------------------------------------------------------------------------
// prefetch first 2 ks of a weight panel (4 frags = 16 VGPR).
// Call ONLY at epilogue end, just before __syncthreads (short live range).
// ---------------------------------------------------------------------------
__device__ __forceinline__ void pf2(const short* __restrict__ wb, bf16x8 pf[4]){
  pf[0] = *(const bf16x8*)(wb);            // tile0 ks0
  pf[1] = *(const bf16x8*)(wb + 256);      // tile1 ks0
  pf[2] = *(const bf16x8*)(wb + 32);       // tile0 ks1
  pf[3] = *(const bf16x8*)(wb + 256 + 32); // tile1 ks1
}

// ---------------------------------------------------------------------------
// mm2 with prefetched ks0-1 (interleaved cols): acc[mt][0] ~ col n0+2*m15,
// acc[mt][1] ~ next col. A: row = 16*mt + (l&15); C rows (l>>4)*4+j.
// Remainder ks=2..7 at unroll 2 (bounded weight hoisting).
// setprio(1) favors MFMA-issuing waves once waves drift (T5).
// ---------------------------------------------------------------------------
__device__ __forceinline__ void mm2_pf(const char* hbuf, const short* __restrict__ wb,
                                       const bf16x8 pf[4], int m15, int g,
                                       f32x4 acc[5][2]){
  __builtin_amdgcn_s_setprio(1);
  #pragma unroll
  for (int ks = 0; ks < 2; ++ks){
    const int kb = ks * 64 + g * 16;
    #pragma unroll
    for (int mt = 0; mt < 5; ++mt){
      const int row = mt * 16 + m15;
      bf16x8 a = *(const bf16x8*)(hbuf + row * 512 + (kb ^ ((row & 7) << 4)));
      acc[mt][0] = __builtin_amdgcn_mfma_f32_16x16x32_bf16(a, ks ? pf[2] : pf[0], acc[mt][0], 0, 0, 0);
      acc[mt][1] = __builtin_amdgcn_mfma_f32_16x16x32_bf16(a, ks ? pf[3] : pf[1], acc[mt][1], 0, 0, 0);
    }
  }
  #pragma unroll 2
  for (int ks = 2; ks < 8; ++ks){
    bf16x8 bf0 = *(const bf16x8*)(wb + ks * 32);
    bf16x8 bf1 = *(const bf16x8*)(wb + 256 + ks * 32);
    const int kb = ks * 64 + g * 16;
    #pragma unroll
    for (int mt = 0; mt < 5; ++mt){
      const int row = mt * 16 + m15;
      bf16x8 a = *(const bf16x8*)(hbuf + row * 512 + (kb ^ ((row & 7) << 4)));
      acc[mt][0] = __builtin_amdgcn_mfma_f32_16x16x32_bf16(a, bf0, acc[mt][0], 0, 0, 0);
      acc[mt][1] = __builtin_amdgcn_mfma_f32_16x16x32_bf16(a, bf1, acc[mt][1], 0, 0, 0);
    }
  }
  __builtin_amdgcn_s_setprio(0);
}

// ---------------------------------------------------------------------------
// Fused GCN. Grid (16, 512). 512 thr = 8 waves, wave w owns cols [32w,32w+32)
// (interleaved pairing). LDS: hA + hB 40KB each; cc (80 x f32x4) overlays hB
// during L0. Row r <-> vertex (v0+r-4) mod 1024. Flow:
// stage cc->hB | L0: cc->hA | L1: hA->hB | L2: hB->hA | L3: hA->hB |
// head1: hB->hA | head2: hA->out.  6 barriers. Next-phase weight pf issued
// at epilogue END (short live range; loads drain during the barrier wait).
// ---------------------------------------------------------------------------
__global__ __launch_bounds__(512, 4)
void gcn_fused(const float* __restrict__ x, const short* __restrict__ ws,
               const float* __restrict__ tvp, const float* __restrict__ cwf,
               const float* __restrict__ b1p, const float* __restrict__ b2p,
               const float* __restrict__ b3p, const float* __restrict__ hb1p,
               const float* __restrict__ hb2p, float* __restrict__ out){
  extern __shared__ char lds[];
  char* const hA = lds;
  char* const hB = lds + 40960;
  const int tid = threadIdx.x;
  const int lane = tid & 63, wid = tid >> 6;
  const int m15 = lane & 15, g = lane >> 4;
  const int n0 = wid * 32;
  const int col0 = n0 + 2 * m15;
  const int cb2 = col0 * 2;             // byte col of this thread's col pair
  const int b = blockIdx.y, v0 = blockIdx.x * 64;

  const int wrow = (n0 + 2 * m15) * 256 + g * 8;
  const short* const wb1 = ws + OFF_W1T + wrow;
  const short* const wb2 = ws + OFF_W2T + wrow;
  const short* const wb3 = ws + OFF_W3T + wrow;
  const short* const wbh = ws + OFF_HW1T + wrow;

  // ---- stage cc[r] = (cagg0, cagg1, c0, c1) f32 into hB[0:1280) ----
  if (tid < 80){
    const int r = tid;
    const float* xb = x + b * 2048;
    int vm = (v0 + r - 5) & (NV - 1);
    int vc = (v0 + r - 4) & (NV - 1);
    int vp = (v0 + r - 3) & (NV - 1);
    float c0m = xb[vm * 2], c1m = xb[vm * 2 + 1];
    float c0c = xb[vc * 2], c1c = xb[vc * 2 + 1];
    float c0p = xb[vp * 2], c1p = xb[vp * 2 + 1];
    f32x4 cc;
    cc[0] = (c0m + c0c + c0p) * (1.f / 3.f);
    cc[1] = (c1m + c1c + c1p) * (1.f / 3.f);
    cc[2] = c0c;
    cc[3] = c1c;
    *(f32x4*)(hB + r * 16) = cc;
  }
  __syncthreads();

  bf16x8 pf[4];

  // ---- layer 0 (rank-5): h1 = silu(tv + cagg@W0c + c@res0c): cc -> hA ----
  {
    const float2 tv2 = *(const float2*)(tvp + b * 256 + col0);
    const float2 wA = *(const float2*)(cwf + col0);
    const float2 wB = *(const float2*)(cwf + 256 + col0);
    const float2 wC = *(const float2*)(cwf + 512 + col0);
    const float2 wD = *(const float2*)(cwf + 768 + col0);
    #pragma unroll
    for (int mt = 0; mt < 5; ++mt){
      const int row0 = mt * 16 + g * 4;
      #pragma unroll
      for (int j = 0; j < 4; ++j){
        const int row = row0 + j;
        const f32x4 cc = *(const f32x4*)(hB + row * 16);
        float s0 = tv2.x + cc[0] * wA.x + cc[1] * wB.x + cc[2] * wC.x + cc[3] * wD.x;
        float s1 = tv2.y + cc[0] * wA.y + cc[1] * wB.y + cc[2] * wC.y + cc[3] * wD.y;
        const int ad = row * 512 + (cb2 ^ ((row & 7) << 4));
        *(unsigned int*)(hA + ad) = pack2_silu(s0, s1);
      }
    }
    __builtin_amdgcn_sched_barrier(0);   // keep pf below the epilogue
    pf2(wb1, pf);                        // drains during the barrier
  }
  __syncthreads();

  f32x4 acc[5][2];

  // ---- layers 1..3: h = silu(agg(h@W') + b + h); W' pre-scaled 1/3;
  //      agg via in-reg shfl; residual read from bin (read-only this phase);
  //      next phase's weight pf at epilogue end ----
  #pragma unroll
  for (int L = 0; L < 3; ++L){
    const char* bin  = (L & 1) ? hB : hA;
    char*       bout = (L & 1) ? hA : hB;
    const short* wbc = (L == 0) ? wb1 : (L == 1) ? wb2 : wb3;
    const float* bp = (L == 0 ? b1p : L == 1 ? b2p : b3p);
    const float2 bias = *(const float2*)(bp + col0);
    #pragma unroll
    for (int mt = 0; mt < 5; ++mt){ acc[mt][0] = zero4(); acc[mt][1] = zero4(); }
    mm2_pf(bin, wbc, pf, m15, g, acc);
    #pragma unroll
    for (int mt = 0; mt < 5; ++mt){
      const int row0 = mt * 16 + g * 4;
      // residual reads first (LDS latency overlaps shfl chain)
      unsigned int rr[4];
      #pragma unroll
      for (int j = 0; j < 4; ++j){
        const int row = row0 + j;
        rr[j] = *(const unsigned int*)(bin + row * 512 + (cb2 ^ ((row & 7) << 4)));
      }
      float pm0[2], pp3[2];
      #pragma unroll
      for (int nt = 0; nt < 2; ++nt){
        float upv = (g == 3) ? acc[mt > 0 ? mt - 1 : 0][nt][3] : acc[mt][nt][3];
        pm0[nt] = __shfl(upv, (lane + 48) & 63);
        float dnv = (g == 0) ? acc[mt < 4 ? mt + 1 : 4][nt][0] : acc[mt][nt][0];
        pp3[nt] = __shfl(dnv, (lane + 16) & 63);
      }
      #pragma unroll
      for (int j = 0; j < 4; ++j){
        const int row = row0 + j;
        const int ad = row * 512 + (cb2 ^ ((row & 7) << 4));
        union { unsigned int i; float f; } re, ro;
        re.i = rr[j] << 16;            // residual, even col
        ro.i = rr[j] & 0xffff0000u;    // residual, odd col
        float p0 = (j == 0) ? pm0[0] : acc[mt][0][j - 1];
        float n0v = (j == 3) ? pp3[0] : acc[mt][0][j + 1];
        float p1 = (j == 0) ? pm0[1] : acc[mt][1][j - 1];
        float n1v = (j == 3) ? pp3[1] : acc[mt][1][j + 1];
        float s0 = p0 + acc[mt][0][j] + n0v + bias.x + re.f;
        float s1 = p1 + acc[mt][1][j] + n1v + bias.y + ro.f;
        *(unsigned int*)(bout + ad) = pack2_silu(s0, s1);
      }
    }
    __builtin_amdgcn_sched_barrier(0);   // keep pf below the epilogue
    pf2((L == 0) ? wb2 : (L == 1) ? wb3 : wbh, pf);
    __syncthreads();
  }
  // h4 now in hB.

  // ---- head part 1: u = silu(h4 @ hW1 + hb1): hB -> hA ----
  {
    const float2 bias = *(const float2*)(hb1p + col0);
    #pragma unroll
    for (int mt = 0; mt < 5; ++mt){ acc[mt][0] = zero4(); acc[mt][1] = zero4(); }
    mm2_pf(hB, wbh, pf, m15, g, acc);
    #pragma unroll
    for (int mt = 0; mt < 5; ++mt){
      const int row0 = mt * 16 + g * 4;
      #pragma unroll
      for (int j = 0; j < 4; ++j){
        const int row = row0 + j;
        const int ad = row * 512 + (cb2 ^ ((row & 7) << 4));
        *(unsigned int*)(hA + ad) =
            pack2_silu(acc[mt][0][j] + bias.x, acc[mt][1][j] + bias.y);
      }
    }
    // head2 weight prefetch at epilogue end (waves 0-4 use it post-barrier)
    __builtin_amdgcn_sched_barrier(0);
    bf16x8 h2a, h2b;
    {
      const short* wbo = ws + OFF_HW2T + m15 * 256 + g * 8;
      h2a = *(const bf16x8*)(wbo);
      h2b = *(const bf16x8*)(wbo + 32);
    }
    __syncthreads();

    // ---- head part 2 (waves 0-4, one mt each): out = u @ hW2 + hb2 ----
    if (wid < 5){
      f32x4 a2 = zero4();
      const short* wbo = ws + OFF_HW2T + m15 * 256 + g * 8;
      const int row = wid * 16 + m15;
      const int rsw = row * 512;
      {
        bf16x8 a0 = *(const bf16x8*)(hA + rsw + ((g * 16) ^ ((row & 7) << 4)));
        a2 = __builtin_amdgcn_mfma_f32_16x16x32_bf16(a0, h2a, a2, 0, 0, 0);
        bf16x8 a1 = *(const bf16x8*)(hA + rsw + ((64 + g * 16) ^ ((row & 7) << 4)));
        a2 = __builtin_amdgcn_mfma_f32_16x16x32_bf16(a1, h2b, a2, 0, 0, 0);
      }
      #pragma unroll 2
      for (int ks = 2; ks < 8; ++ks){
        bf16x8 bfr = *(const bf16x8*)(wbo + ks * 32);
        const int kb = ks * 64 + g * 16;
        bf16x8 a = *(const bf16x8*)(hA + rsw + (kb ^ ((row & 7) << 4)));
        a2 = __builtin_amdgcn_mfma_f32_16x16x32_bf16(a, bfr, a2, 0, 0, 0);
      }
      if (m15 < 2){
        float bias = hb2p[m15];
        #pragma unroll
        for (int j = 0; j < 4; ++j){
          int orow = wid * 16 + g * 4 + j;
          if (orow >= 4 && orow < 68)
            out[b * 2048 + (v0 + orow - 4) * 2 + m15] = a2[j] + bias;
        }
      }
    }
  }
}

// ---------------------------------------------------------------------------
extern "C" void kernel_launch(void* const* d_in, const int* in_sizes, int n_in,
                              void* d_out, int out_size, void* d_ws, size_t ws_size,
                              hipStream_t stream){
  const float* x   = (const float*)d_in[0];
  const int*   t   = (const int*)  d_in[1];
  const float* tW  = (const float*)d_in[2];
  const float* tb  = (const float*)d_in[3];
  const float* W0  = (const float*)d_in[4];
  const float* b0  = (const float*)d_in[5];
  const float* W1  = (const float*)d_in[6];
  const float* b1  = (const float*)d_in[7];
  const float* W2  = (const float*)d_in[8];
  const float* b2  = (const float*)d_in[9];
  const float* W3  = (const float*)d_in[10];
  const float* b3  = (const float*)d_in[11];
  const float* res0= (const float*)d_in[12];
  const float* hW1 = (const float*)d_in[13];
  const float* hb1 = (const float*)d_in[14];
  const float* hW2 = (const float*)d_in[15];
  const float* hb2 = (const float*)d_in[16];
  short* ws  = (short*)d_ws;
  float* tvp = (float*)((char*)d_ws + TV_BYTE);
  float* cwf = (float*)((char*)d_ws + CW_BYTE);
  float* out = (float*)d_out;

  hipFuncSetAttribute((const void*)gcn_fused,
                      hipFuncAttributeMaxDynamicSharedMemorySize, 81920);

  prep_kernel<<<dim3((PREP_TOTAL + 255) / 256), dim3(256), 0, stream>>>(
      W0, res0, W1, W2, W3, hW1, hW2, ws);
  temb_kernel<<<dim3(512), dim3(256), 0, stream>>>(t, tW, tb, W0, res0, b0, tvp);
  gcn_fused<<<dim3(16, 512), dim3(512), 81920, stream>>>(
      x, ws, tvp, cwf, b1, b2, b3, hb1, hb2, out);
}